// Round 14
// baseline (218.428 us; speedup 1.0000x reference)
//
#include <hip/hip_runtime.h>
#include <math.h>

#define HID 128
#define NF  128
#define NG  50

typedef unsigned short ushort_t;
typedef unsigned short us8 __attribute__((ext_vector_type(8)));
typedef unsigned short us4 __attribute__((ext_vector_type(4)));
typedef unsigned short us2 __attribute__((ext_vector_type(2)));
typedef __bf16 bf16x8 __attribute__((ext_vector_type(8)));
typedef float f32x4 __attribute__((ext_vector_type(4)));

__device__ inline float ssp_fast(float x) {
    // softplus(x) - ln2 = max(x,0) + ln2*(log2(1+exp2(-|x|*log2e)) - 1)
    float t = __builtin_amdgcn_exp2f(fabsf(x) * -1.4426950408889634f);
    float l = __builtin_amdgcn_logf(1.0f + t);      // log2
    return fmaxf(x, 0.0f) + 0.6931471805599453f * (l - 1.0f);
}

__device__ inline ushort_t f2bf(float f) {
    return __builtin_bit_cast(ushort_t, (__bf16)f);
}
__device__ inline float bf2f(ushort_t h) {
    unsigned u = ((unsigned)h) << 16;
    return __builtin_bit_cast(float, u);
}

// async global->LDS, 16B per lane; LDS dest wave-uniform, global src per-lane
__device__ inline void gload16(const void* g, void* l) {
    __builtin_amdgcn_global_load_lds(
        (const __attribute__((address_space(1))) void*)g,
        (__attribute__((address_space(3))) void*)l, 16, 0, 0);
}

// ------- merged count_slots + weight prep + pad zero + ea bf16 pack --------
// eabl[e][64]: bf16, 128B-aligned rows (cols 50..63 zero) -> 2-line gathers.
__global__ void prep_count(const int* __restrict__ dstI, int* counts,
                           int* __restrict__ slot,
                           const float* __restrict__ lin1_w,
                           const float* __restrict__ lin2_w,
                           const float* __restrict__ lin_w,
                           const float* __restrict__ mlp_w0,
                           const float* __restrict__ mlp_w2,
                           const float* __restrict__ ea,
                           ushort_t* __restrict__ l1b,
                           ushort_t* __restrict__ l2b,
                           ushort_t* __restrict__ lfb,
                           ushort_t* __restrict__ w0g,
                           ushort_t* __restrict__ w2g,
                           ushort_t* __restrict__ eabl,
                           int* __restrict__ sidecar_pad,
                           int E, int nsp) {
    int idx = blockIdx.x * 256 + threadIdx.x;
    if (idx < E) {
        slot[idx] = atomicAdd(&counts[dstI[idx]], 1);
        return;
    }
    int k = idx - E;
    if (k < 49152) {
        int m = k >> 14, i = k & 16383;
        int o = i >> 7, kk = i & 127;
        const float* s = (m == 0) ? lin1_w : (m == 1) ? lin2_w : lin_w;
        ushort_t*    d = (m == 0) ? l1b    : (m == 1) ? l2b    : lfb;
        d[o * 128 + (kk ^ ((o & 7) << 3))] = f2bf(s[i]);
    } else if (k < 57344) {
        int i = k - 49152;              // o*64 + kk
        int o = i >> 6, kk = i & 63;
        float v = (kk < 50) ? mlp_w0[o * 50 + kk] : 0.f;
        w0g[i] = f2bf(v);
    } else if (k < 73728) {
        int i = k - 57344;              // o*128 + kk
        w2g[i] = f2bf(mlp_w2[i]);
    } else if (k < 73728 + nsp) {
        sidecar_pad[k - 73728] = 0;
    } else {
        int j = k - 73728 - nsp;        // 0 .. 8E-1
        int e = j >> 3, q = j & 7;
        const float* row = ea + (size_t)e * 50;
        us8 v = {0, 0, 0, 0, 0, 0, 0, 0};
        #pragma unroll
        for (int x = 0; x < 4; ++x) {
            int col = q * 8 + x * 2;
            if (col < 50) {
                float2 f = *(const float2*)(row + col);
                v[2 * x]     = f2bf(f.x);
                v[2 * x + 1] = f2bf(f.y);
            }
        }
        *(us8*)&eabl[(size_t)e * 64 + q * 8] = v;
    }
}

// ---------------- scan1: block-local exclusive + per-block totals -----------
__global__ __launch_bounds__(1024) void scan1(const int* __restrict__ counts,
                                              int* __restrict__ off,
                                              int* __restrict__ bsum, int n) {
    __shared__ int s[1024];
    int t = threadIdx.x, g = blockIdx.x * 1024 + t;
    int c = (g < n) ? counts[g] : 0;
    s[t] = c;
    __syncthreads();
    for (int d = 1; d < 1024; d <<= 1) {
        int v = (t >= d) ? s[t - d] : 0;
        __syncthreads();
        s[t] += v;
        __syncthreads();
    }
    if (g < n) off[g] = s[t] - c;             // block-local exclusive
    if (t == 1023) bsum[blockIdx.x] = s[1023];
}

// ---------------- fused: gemm_h1 blocks + permute blocks --------------------
__global__ __launch_bounds__(1024, 4) void h1_and_permute(
    const float* __restrict__ A, const ushort_t* __restrict__ Wb,
    ushort_t* __restrict__ h1b, float* __restrict__ aggz, int n_rows, int ngrid,
    const int* __restrict__ srcI, const int* __restrict__ dstI,
    const int* __restrict__ slot, const int* __restrict__ off,
    const int* __restrict__ bsum, int nsb, const float* __restrict__ ew,
    int4* __restrict__ sidecar, int E)
{
    __shared__ ushort_t a_s[128 * 128];
    __shared__ ushort_t w_s[128 * 128];
    const int tid = threadIdx.x;

    if (blockIdx.x >= ngrid) {
        // ---------------- permute branch ----------------
        int* cs  = (int*)a_s;          // 64 ints: inclusive scan
        int* cse = (int*)a_s + 64;     // 64 ints: exclusive carries
        int own = 0;
        if (tid < 64) {
            own = (tid < nsb) ? bsum[tid] : 0;
            cs[tid] = own;
        }
        __syncthreads();
        for (int d = 1; d < 64; d <<= 1) {
            int v = 0;
            if (tid < 64 && tid >= d) v = cs[tid - d];
            __syncthreads();
            if (tid < 64) cs[tid] += v;
            __syncthreads();
        }
        if (tid < 64) cse[tid] = cs[tid] - own;
        __syncthreads();

        int e = (blockIdx.x - ngrid) * 1024 + tid;
        if (e < E) {
            int d = dstI[e];
            int p = off[d] + cse[d >> 10] + slot[e];
            float cw = 0.5f * (__builtin_amdgcn_cosf(ew[e] * 0.05f) + 1.0f);
            sidecar[p] = make_int4(srcI[e], d, __float_as_int(cw), e);
        }
        return;
    }

    // ---------------- gemm_h1 branch ----------------
    const int n0 = blockIdx.x * 128;
    const int lane = tid & 63, wid = tid >> 6;

    #pragma unroll
    for (int i = 0; i < 2; ++i) {
        int cid = wid * 2 + i;
        gload16(Wb + cid * 512 + lane * 8, w_s + cid * 512);
    }
    {
        int r = tid >> 3, q = tid & 7;
        int n = n0 + r;
        float vals[16];
        if (n < n_rows) {
            #pragma unroll
            for (int j = 0; j < 4; ++j) {
                f32x4 v = ((const f32x4*)A)[(size_t)n * 32 + q * 4 + j];
                #pragma unroll
                for (int x = 0; x < 4; ++x) vals[j * 4 + x] = v[x];
            }
        } else {
            #pragma unroll
            for (int x = 0; x < 16; ++x) vals[x] = 0.f;
        }
        int sw = (r & 7) << 3;
        #pragma unroll
        for (int hh = 0; hh < 2; ++hh) {
            us8 pk;
            #pragma unroll
            for (int x = 0; x < 8; ++x) pk[x] = f2bf(vals[hh * 8 + x]);
            *(us8*)&a_s[r * 128 + ((q * 16 + hh * 8) ^ sw)] = pk;
        }
    }
    __syncthreads();

    const int og = (wid >> 2) * 32;
    const int rg = (wid & 3) * 32;
    const int lm = lane & 15, lh = lane >> 4;

    f32x4 acc[2][2];
    #pragma unroll
    for (int mt = 0; mt < 2; ++mt)
        #pragma unroll
        for (int nt = 0; nt < 2; ++nt) acc[mt][nt] = (f32x4){0.f, 0.f, 0.f, 0.f};

    #pragma unroll
    for (int ks = 0; ks < 4; ++ks) {
        int k8 = ks * 32 + lh * 8;
        bf16x8 af[2], wf[2];
        #pragma unroll
        for (int mt = 0; mt < 2; ++mt) {
            int m = rg + mt * 16 + lm;
            af[mt] = __builtin_bit_cast(bf16x8,
                *(const us8*)&a_s[m * 128 + (k8 ^ ((m & 7) << 3))]);
        }
        #pragma unroll
        for (int nt = 0; nt < 2; ++nt) {
            int n = og + nt * 16 + lm;
            wf[nt] = __builtin_bit_cast(bf16x8,
                *(const us8*)&w_s[n * 128 + (k8 ^ ((n & 7) << 3))]);
        }
        #pragma unroll
        for (int mt = 0; mt < 2; ++mt)
            #pragma unroll
            for (int nt = 0; nt < 2; ++nt)
                acc[mt][nt] = __builtin_amdgcn_mfma_f32_16x16x32_bf16(
                    af[mt], wf[nt], acc[mt][nt], 0, 0, 0);
    }

    #pragma unroll
    for (int nt = 0; nt < 2; ++nt) {
        int outc = og + nt * 16 + lm;
        #pragma unroll
        for (int mt = 0; mt < 2; ++mt) {
            int rbase = rg + mt * 16 + lh * 4;
            #pragma unroll
            for (int j = 0; j < 4; ++j) {
                int n = n0 + rbase + j;
                if (n < n_rows) {
                    h1b[(size_t)n * 128 + outc] = f2bf(acc[mt][nt][j]);
                    aggz[(size_t)n * 128 + outc] = 0.f;
                }
            }
        }
    }
}

// ---------------- fused node GEMM2+3 (reads h1b bf16 + agg f32) -------------
__global__ __launch_bounds__(1024, 4) void gemm23_fused(
    const ushort_t* __restrict__ h1b, const float* __restrict__ agg,
    const ushort_t* __restrict__ l2b, const float* __restrict__ b2,
    const ushort_t* __restrict__ lfb, const float* __restrict__ lb,
    float* __restrict__ outF, int n_rows)
{
    __shared__ ushort_t a_s[128 * 128];
    __shared__ ushort_t w_s[128 * 128];
    const int tid = threadIdx.x;
    const int n0 = blockIdx.x * 128;
    const int lane = tid & 63, wid = tid >> 6;

    #pragma unroll
    for (int i = 0; i < 2; ++i) {
        int cid = wid * 2 + i;
        gload16(l2b + cid * 512 + lane * 8, w_s + cid * 512);
    }
    {
        int r = tid >> 3, q = tid & 7;
        int n = n0 + r;
        float vals[16];
        if (n < n_rows) {
            us8 hb0 = *(const us8*)&h1b[(size_t)n * 128 + q * 16];
            us8 hb1 = *(const us8*)&h1b[(size_t)n * 128 + q * 16 + 8];
            #pragma unroll
            for (int j = 0; j < 4; ++j) {
                f32x4 av = ((const f32x4*)agg)[(size_t)n * 32 + q * 4 + j];
                #pragma unroll
                for (int x = 0; x < 4; ++x) {
                    int c = j * 4 + x;
                    float hv = bf2f(c < 8 ? hb0[c] : hb1[c - 8]);
                    vals[c] = hv + av[x];
                }
            }
        } else {
            #pragma unroll
            for (int x = 0; x < 16; ++x) vals[x] = 0.f;
        }
        int sw = (r & 7) << 3;
        #pragma unroll
        for (int hh = 0; hh < 2; ++hh) {
            us8 pk;
            #pragma unroll
            for (int x = 0; x < 8; ++x) pk[x] = f2bf(vals[hh * 8 + x]);
            *(us8*)&a_s[r * 128 + ((q * 16 + hh * 8) ^ sw)] = pk;
        }
    }
    __syncthreads();

    const int og = (wid >> 2) * 32;
    const int rg = (wid & 3) * 32;
    const int lm = lane & 15, lh = lane >> 4;

    f32x4 acc[2][2];
    #pragma unroll
    for (int mt = 0; mt < 2; ++mt)
        #pragma unroll
        for (int nt = 0; nt < 2; ++nt) acc[mt][nt] = (f32x4){0.f, 0.f, 0.f, 0.f};
    #pragma unroll
    for (int ks = 0; ks < 4; ++ks) {
        int k8 = ks * 32 + lh * 8;
        bf16x8 af[2], wf[2];
        #pragma unroll
        for (int mt = 0; mt < 2; ++mt) {
            int m = rg + mt * 16 + lm;
            af[mt] = __builtin_bit_cast(bf16x8,
                *(const us8*)&a_s[m * 128 + (k8 ^ ((m & 7) << 3))]);
        }
        #pragma unroll
        for (int nt = 0; nt < 2; ++nt) {
            int n = og + nt * 16 + lm;
            wf[nt] = __builtin_bit_cast(bf16x8,
                *(const us8*)&w_s[n * 128 + (k8 ^ ((n & 7) << 3))]);
        }
        #pragma unroll
        for (int mt = 0; mt < 2; ++mt)
            #pragma unroll
            for (int nt = 0; nt < 2; ++nt)
                acc[mt][nt] = __builtin_amdgcn_mfma_f32_16x16x32_bf16(
                    af[mt], wf[nt], acc[mt][nt], 0, 0, 0);
    }
    __syncthreads();        // all a_s / w_s reads complete

    #pragma unroll
    for (int i = 0; i < 2; ++i) {
        int cid = wid * 2 + i;
        gload16(lfb + cid * 512 + lane * 8, w_s + cid * 512);
    }
    #pragma unroll
    for (int nt = 0; nt < 2; ++nt) {
        int outc = og + nt * 16 + lm;
        float bv = b2[outc];
        #pragma unroll
        for (int mt = 0; mt < 2; ++mt) {
            int rbase = rg + mt * 16 + lh * 4;
            #pragma unroll
            for (int j = 0; j < 4; ++j) {
                int r = rbase + j;
                a_s[r * 128 + (outc ^ ((r & 7) << 3))] =
                    f2bf(ssp_fast(acc[mt][nt][j] + bv));
            }
        }
    }
    __syncthreads();

    f32x4 acc2[2][2];
    #pragma unroll
    for (int mt = 0; mt < 2; ++mt)
        #pragma unroll
        for (int nt = 0; nt < 2; ++nt) acc2[mt][nt] = (f32x4){0.f, 0.f, 0.f, 0.f};
    #pragma unroll
    for (int ks = 0; ks < 4; ++ks) {
        int k8 = ks * 32 + lh * 8;
        bf16x8 af[2], wf[2];
        #pragma unroll
        for (int mt = 0; mt < 2; ++mt) {
            int m = rg + mt * 16 + lm;
            af[mt] = __builtin_bit_cast(bf16x8,
                *(const us8*)&a_s[m * 128 + (k8 ^ ((m & 7) << 3))]);
        }
        #pragma unroll
        for (int nt = 0; nt < 2; ++nt) {
            int n = og + nt * 16 + lm;
            wf[nt] = __builtin_bit_cast(bf16x8,
                *(const us8*)&w_s[n * 128 + (k8 ^ ((n & 7) << 3))]);
        }
        #pragma unroll
        for (int mt = 0; mt < 2; ++mt)
            #pragma unroll
            for (int nt = 0; nt < 2; ++nt)
                acc2[mt][nt] = __builtin_amdgcn_mfma_f32_16x16x32_bf16(
                    af[mt], wf[nt], acc2[mt][nt], 0, 0, 0);
    }

    #pragma unroll
    for (int nt = 0; nt < 2; ++nt) {
        int outc = og + nt * 16 + lm;
        float bv = lb[outc];
        #pragma unroll
        for (int mt = 0; mt < 2; ++mt) {
            int rbase = rg + mt * 16 + lh * 4;
            #pragma unroll
            for (int j = 0; j < 4; ++j) {
                int n = n0 + rbase + j;
                if (n < n_rows)
                    outF[(size_t)n * 128 + outc] = acc2[mt][nt][j] + bv;
            }
        }
    }
}

// ---------------- fused edge MLP + message + segmented aggregation ---------
// 512 thr = 8 waves (4 out-groups x 2 edge-groups); 128 CSR positions/block.
// ea gathered from eabl (bf16, 128B-aligned rows -> 2 lines/row).
__global__ __launch_bounds__(512, 6) void edge_fused(
    const ushort_t* __restrict__ eabl, const int4* __restrict__ sidecar,
    const ushort_t* __restrict__ w0g, const ushort_t* __restrict__ w2g,
    const float* __restrict__ b0g, const float* __restrict__ b2g,
    const ushort_t* __restrict__ h1b, float* __restrict__ agg, int E)
{
    __shared__ __align__(16) char blob[50688];
    ushort_t* ea_s = (ushort_t*)blob;             // 16 KB [0,16384)
    ushort_t* u_s  = (ushort_t*)(blob + 16384);   // 32 KB [16384,49152)
    ushort_t* m_sb = (ushort_t*)blob;             // 32 KB overlay (phase D/E)
    float* cws = (float*)(blob + 49152);          // 512 B
    int* srcs  = (int*)(blob + 49664);            // 512 B
    int* dsts  = (int*)(blob + 50176);            // 512 B

    const int tid = threadIdx.x;
    const int p0 = blockIdx.x * 128;
    const int lane = tid & 63, wid = tid >> 6;
    const int out0w = (wid >> 1) * 32;   // 4 out-groups of 32
    const int e0w   = (wid & 1) * 64;    // 2 edge-groups of 64
    const int lm = lane & 15, lh = lane >> 4;

    // ---- stage ea rows by gather: 4 threads/row, 2 aligned 16B loads ----
    {
        int r = tid >> 2, q = tid & 3;   // 128 rows x 4 chunks of 16 elems
        int p = p0 + r;
        int eidx = ((const int*)sidecar)[(size_t)p * 4 + 3];
        const us8* rowp = (const us8*)(eabl + (size_t)eidx * 64);
        us8 v0 = rowp[q * 2];
        us8 v1 = rowp[q * 2 + 1];
        int sw = (r & 7) << 3;
        *(us8*)&ea_s[r * 64 + ((q * 16)     ^ sw)] = v0;
        *(us8*)&ea_s[r * 64 + ((q * 16 + 8) ^ sw)] = v1;
    }
    if (tid < 128) {
        int4 sc = sidecar[p0 + tid];
        srcs[tid] = sc.x; dsts[tid] = sc.y; cws[tid] = __int_as_float(sc.z);
    }

    // w0 fragments (L2-resident)
    bf16x8 w0f[2][2];
    #pragma unroll
    for (int ks = 0; ks < 2; ++ks)
        #pragma unroll
        for (int mt = 0; mt < 2; ++mt) {
            int n = out0w + mt * 16 + lm;
            w0f[ks][mt] = __builtin_bit_cast(bf16x8,
                *(const us8*)&w0g[n * 64 + ks * 32 + lh * 8]);
        }
    __syncthreads();

    // ---- GEMM1: t^T = w0 * ea^T  (K = 64 padded) ----
    f32x4 acc1[2][4];
    #pragma unroll
    for (int mt = 0; mt < 2; ++mt)
        #pragma unroll
        for (int nt = 0; nt < 4; ++nt) acc1[mt][nt] = (f32x4){0.f, 0.f, 0.f, 0.f};
    #pragma unroll
    for (int ks = 0; ks < 2; ++ks) {
        int k8 = ks * 32 + lh * 8;
        #pragma unroll
        for (int nt = 0; nt < 4; ++nt) {
            int e = e0w + nt * 16 + lm;
            bf16x8 be = __builtin_bit_cast(bf16x8,
                *(const us8*)&ea_s[e * 64 + (k8 ^ ((e & 7) << 3))]);
            #pragma unroll
            for (int mt = 0; mt < 2; ++mt)
                acc1[mt][nt] = __builtin_amdgcn_mfma_f32_16x16x32_bf16(
                    w0f[ks][mt], be, acc1[mt][nt], 0, 0, 0);
        }
    }

    // epilogue1: u = ssp(t + b0) -> packed 4xbf16 ds_write_b64
    #pragma unroll
    for (int mt = 0; mt < 2; ++mt) {
        int out0 = out0w + mt * 16 + lh * 4;
        f32x4 b0v = *(const f32x4*)&b0g[out0];
        #pragma unroll
        for (int nt = 0; nt < 4; ++nt) {
            int e = e0w + nt * 16 + lm;
            us4 pk;
            #pragma unroll
            for (int j = 0; j < 4; ++j)
                pk[j] = f2bf(ssp_fast(acc1[mt][nt][j] + b0v[j]));
            *(us4*)&u_s[e * 128 + (out0 ^ ((e & 7) << 3))] = pk;
        }
    }

    // w2 fragments loaded here (L2-hit, hidden under epilogue/barrier)
    bf16x8 w2f[4][2];
    #pragma unroll
    for (int ks = 0; ks < 4; ++ks)
        #pragma unroll
        for (int mt = 0; mt < 2; ++mt) {
            int n = out0w + mt * 16 + lm;
            w2f[ks][mt] = __builtin_bit_cast(bf16x8,
                *(const us8*)&w2g[n * 128 + ks * 32 + lh * 8]);
        }
    __syncthreads();

    // ---- GEMM2: W^T = w2 * u^T  (K = 128) ----
    f32x4 acc2[2][4];
    #pragma unroll
    for (int mt = 0; mt < 2; ++mt)
        #pragma unroll
        for (int nt = 0; nt < 4; ++nt) acc2[mt][nt] = (f32x4){0.f, 0.f, 0.f, 0.f};
    #pragma unroll
    for (int ks = 0; ks < 4; ++ks) {
        int k8 = ks * 32 + lh * 8;
        #pragma unroll
        for (int nt = 0; nt < 4; ++nt) {
            int e = e0w + nt * 16 + lm;
            bf16x8 be = __builtin_bit_cast(bf16x8,
                *(const us8*)&u_s[e * 128 + (k8 ^ ((e & 7) << 3))]);
            #pragma unroll
            for (int mt = 0; mt < 2; ++mt)
                acc2[mt][nt] = __builtin_amdgcn_mfma_f32_16x16x32_bf16(
                    w2f[ks][mt], be, acc2[mt][nt], 0, 0, 0);
        }
    }
    __syncthreads();    // ea_s/u_s reads done; m_sb overlay now safe

    // ---- phase D: W' = c*(W+b2) -> bf16 LDS (swizzled), no h1 ----
    #pragma unroll
    for (int mt = 0; mt < 2; ++mt) {
        int out0 = out0w + mt * 16 + lh * 4;
        f32x4 b2v = *(const f32x4*)&b2g[out0];
        #pragma unroll
        for (int nt = 0; nt < 4; ++nt) {
            int e = e0w + nt * 16 + lm;
            float cvv = cws[e];
            us4 pk;
            #pragma unroll
            for (int j = 0; j < 4; ++j)
                pk[j] = f2bf(cvv * (acc2[mt][nt][j] + b2v[j]));
            *(us4*)&m_sb[e * 128 + (out0 ^ ((e & 7) << 2))] = pk;
        }
    }

    // hoisted phase-E h1 prefetch (accumulators dead -> regs free)
    const int i0 = wid * 16;             // 8 segments x 16 edges
    us2 h1r[16];
    #pragma unroll
    for (int j = 0; j < 16; ++j) {
        int s = srcs[i0 + j];
        h1r[j] = *(const us2*)&h1b[(size_t)s * 128 + lane * 2];
    }
    __syncthreads();

    // ---- phase E: segmented reduce + atomics ----
    {
        const int cp = lane;             // ch pair: channels 2cp, 2cp+1
        float sx = 0.f, sy = 0.f;
        int prev = dsts[i0];
        #pragma unroll
        for (int j = 0; j < 16; ++j) {
            int i = i0 + j;
            int d = dsts[i];
            us2 wv = *(const us2*)&m_sb[i * 128 + ((cp * 2) ^ ((i & 7) << 2))];
            if (d != prev) {
                atomicAdd(&agg[(size_t)prev * 128 + cp * 2], sx);
                atomicAdd(&agg[(size_t)prev * 128 + cp * 2 + 1], sy);
                sx = 0.f; sy = 0.f; prev = d;
            }
            sx += bf2f(wv[0]) * bf2f(h1r[j][0]);
            sy += bf2f(wv[1]) * bf2f(h1r[j][1]);
        }
        atomicAdd(&agg[(size_t)prev * 128 + cp * 2], sx);
        atomicAdd(&agg[(size_t)prev * 128 + cp * 2 + 1], sy);
    }
}

extern "C" void kernel_launch(void* const* d_in, const int* in_sizes, int n_in,
                              void* d_out, int out_size, void* d_ws, size_t ws_size,
                              hipStream_t stream) {
    const float* h       = (const float*)d_in[0];
    const int*   ei      = (const int*)  d_in[1];
    const float* ew      = (const float*)d_in[2];
    const float* ea      = (const float*)d_in[3];
    const float* mlp_w0  = (const float*)d_in[4];
    const float* mlp_b0  = (const float*)d_in[5];
    const float* mlp_w2  = (const float*)d_in[6];
    const float* mlp_b2  = (const float*)d_in[7];
    const float* lin1_w  = (const float*)d_in[8];
    const float* lin2_w  = (const float*)d_in[9];
    const float* lin2_b  = (const float*)d_in[10];
    const float* lin_w   = (const float*)d_in[11];
    const float* lin_b   = (const float*)d_in[12];
    float* out = (float*)d_out;
    float* ws  = (float*)d_ws;

    const int N = in_sizes[0] / HID;            // 50000
    const int E = in_sizes[2];                  // 600000
    const int PADE = (E + 127) & ~127;          // 600064
    const int NODE_PAD = (N + 256) & ~255;      // 50176
    const int NSB = (N + 1023) / 1024;          // 49 scan blocks

    // ---- workspace layout (f32 slots) ----
    float* agg   = ws;                                   // N*128
    ushort_t* h1b = (ushort_t*)(agg + (size_t)N * 128);  // N*128 us
    ushort_t* l1b = (ushort_t*)((float*)h1b + (size_t)N * 64);
    ushort_t* l2b = l1b + 16384;
    ushort_t* lfb = l2b + 16384;
    ushort_t* w0g = lfb + 16384;                         // 8192 us
    ushort_t* w2g = w0g + 8192;                          // 16384 us
    int* counts  = (int*)(w2g + 16384);                  // NODE_PAD
    int* off     = counts + NODE_PAD;                    // NODE_PAD
    int* bsum    = off + NODE_PAD;                       // 64
    int* slot    = bsum + 64;                            // E
    int4* sidecar = (int4*)(slot + E);                   // PADE int4
    ushort_t* eabl = (ushort_t*)(sidecar + PADE);        // E*64 us (128B rows)

    const int* srcI = ei;
    const int* dstI = ei + E;

    hipMemsetAsync(counts, 0, (size_t)NODE_PAD * 4, stream);

    const int nsp = (PADE - E) * 4;    // sidecar pad ints
    long long total_threads = (long long)E + 73728 + nsp + (long long)E * 8;
    prep_count<<<(int)((total_threads + 255) / 256), 256, 0, stream>>>(
        dstI, counts, slot, lin1_w, lin2_w, lin_w, mlp_w0, mlp_w2, ea,
        l1b, l2b, lfb, w0g, w2g, eabl, (int*)(sidecar + E), E, nsp);

    scan1<<<NSB, 1024, 0, stream>>>(counts, off, bsum, N);

    int ngrid = (N + 127) / 128;                // 391
    int pb    = (E + 1023) / 1024;              // 586
    // fused: h1b = bf16(h @ lin1^T) + agg=0  ||  sidecar permute (+scan2)
    h1_and_permute<<<ngrid + pb, 1024, 0, stream>>>(
        h, l1b, h1b, agg, N, ngrid,
        srcI, dstI, slot, off, bsum, NSB, ew, sidecar, E);

    // fused edge MLP + message + aggregation (eabl gathered in-kernel)
    edge_fused<<<PADE / 128, 512, 0, stream>>>(eabl, sidecar, w0g, w2g,
                                               mlp_b0, mlp_b2, h1b, agg, E);

    // out = ssp((h1+agg)@lin2^T + b2) @ lin^T + lin_b
    gemm23_fused<<<ngrid, 1024, 0, stream>>>(h1b, agg, l2b, lin2_b,
                                             lfb, lin_b, out, N);
}

// Round 15
// 178.040 us; speedup vs baseline: 1.2268x; 1.2268x over previous
//
#include <hip/hip_runtime.h>
#include <math.h>

#define HID 128
#define NF  128
#define NG  50

typedef unsigned short ushort_t;
typedef unsigned short us8 __attribute__((ext_vector_type(8)));
typedef unsigned short us4 __attribute__((ext_vector_type(4)));
typedef unsigned short us2 __attribute__((ext_vector_type(2)));
typedef __bf16 bf16x8 __attribute__((ext_vector_type(8)));
typedef float f32x4 __attribute__((ext_vector_type(4)));

__device__ inline float ssp_fast(float x) {
    // softplus(x) - ln2 = max(x,0) + ln2*(log2(1+exp2(-|x|*log2e)) - 1)
    float t = __builtin_amdgcn_exp2f(fabsf(x) * -1.4426950408889634f);
    float l = __builtin_amdgcn_logf(1.0f + t);      // log2
    return fmaxf(x, 0.0f) + 0.6931471805599453f * (l - 1.0f);
}

__device__ inline ushort_t f2bf(float f) {
    return __builtin_bit_cast(ushort_t, (__bf16)f);
}
__device__ inline float bf2f(ushort_t h) {
    unsigned u = ((unsigned)h) << 16;
    return __builtin_bit_cast(float, u);
}

// async global->LDS, 16B per lane; LDS dest wave-uniform, global src per-lane
__device__ inline void gload16(const void* g, void* l) {
    __builtin_amdgcn_global_load_lds(
        (const __attribute__((address_space(1))) void*)g,
        (__attribute__((address_space(3))) void*)l, 16, 0, 0);
}

// ---------------- merged count_slots + weight prep + pad zero ---------------
__global__ void prep_count(const int* __restrict__ dstI, int* counts,
                           int* __restrict__ slot,
                           const float* __restrict__ lin1_w,
                           const float* __restrict__ lin2_w,
                           const float* __restrict__ lin_w,
                           const float* __restrict__ mlp_w0,
                           const float* __restrict__ mlp_w2,
                           ushort_t* __restrict__ l1b,
                           ushort_t* __restrict__ l2b,
                           ushort_t* __restrict__ lfb,
                           ushort_t* __restrict__ w0g,
                           ushort_t* __restrict__ w2g,
                           int* __restrict__ sidecar_pad,
                           int E, int nsp) {
    int idx = blockIdx.x * 256 + threadIdx.x;
    if (idx < E) {
        slot[idx] = atomicAdd(&counts[dstI[idx]], 1);
        return;
    }
    int k = idx - E;
    if (k < 49152) {
        int m = k >> 14, i = k & 16383;
        int o = i >> 7, kk = i & 127;
        const float* s = (m == 0) ? lin1_w : (m == 1) ? lin2_w : lin_w;
        ushort_t*    d = (m == 0) ? l1b    : (m == 1) ? l2b    : lfb;
        d[o * 128 + (kk ^ ((o & 7) << 3))] = f2bf(s[i]);
    } else if (k < 57344) {
        int i = k - 49152;              // o*64 + kk
        int o = i >> 6, kk = i & 63;
        float v = (kk < 50) ? mlp_w0[o * 50 + kk] : 0.f;
        w0g[i] = f2bf(v);
    } else if (k < 73728) {
        int i = k - 57344;              // o*128 + kk
        w2g[i] = f2bf(mlp_w2[i]);
    } else if (k < 73728 + nsp) {
        sidecar_pad[k - 73728] = 0;
    }
}

// ---------------- scan1: block-local exclusive + per-block totals -----------
__global__ __launch_bounds__(1024) void scan1(const int* __restrict__ counts,
                                              int* __restrict__ off,
                                              int* __restrict__ bsum, int n) {
    __shared__ int s[1024];
    int t = threadIdx.x, g = blockIdx.x * 1024 + t;
    int c = (g < n) ? counts[g] : 0;
    s[t] = c;
    __syncthreads();
    for (int d = 1; d < 1024; d <<= 1) {
        int v = (t >= d) ? s[t - d] : 0;
        __syncthreads();
        s[t] += v;
        __syncthreads();
    }
    if (g < n) off[g] = s[t] - c;             // block-local exclusive
    if (t == 1023) bsum[blockIdx.x] = s[1023];
}

// ---------------- fused: gemm_h1 blocks + permute blocks --------------------
__global__ __launch_bounds__(1024, 4) void h1_and_permute(
    const float* __restrict__ A, const ushort_t* __restrict__ Wb,
    ushort_t* __restrict__ h1b, float* __restrict__ aggz, int n_rows, int ngrid,
    const int* __restrict__ srcI, const int* __restrict__ dstI,
    const int* __restrict__ slot, const int* __restrict__ off,
    const int* __restrict__ bsum, int nsb, const float* __restrict__ ew,
    int4* __restrict__ sidecar, int E)
{
    __shared__ ushort_t a_s[128 * 128];
    __shared__ ushort_t w_s[128 * 128];
    const int tid = threadIdx.x;

    if (blockIdx.x >= ngrid) {
        // ---------------- permute branch ----------------
        int* cs  = (int*)a_s;          // 64 ints: inclusive scan
        int* cse = (int*)a_s + 64;     // 64 ints: exclusive carries
        int own = 0;
        if (tid < 64) {
            own = (tid < nsb) ? bsum[tid] : 0;
            cs[tid] = own;
        }
        __syncthreads();
        for (int d = 1; d < 64; d <<= 1) {
            int v = 0;
            if (tid < 64 && tid >= d) v = cs[tid - d];
            __syncthreads();
            if (tid < 64) cs[tid] += v;
            __syncthreads();
        }
        if (tid < 64) cse[tid] = cs[tid] - own;
        __syncthreads();

        int e = (blockIdx.x - ngrid) * 1024 + tid;
        if (e < E) {
            int d = dstI[e];
            int p = off[d] + cse[d >> 10] + slot[e];
            float cw = 0.5f * (__builtin_amdgcn_cosf(ew[e] * 0.05f) + 1.0f);
            sidecar[p] = make_int4(srcI[e], d, __float_as_int(cw), e);
        }
        return;
    }

    // ---------------- gemm_h1 branch ----------------
    const int n0 = blockIdx.x * 128;
    const int lane = tid & 63, wid = tid >> 6;

    #pragma unroll
    for (int i = 0; i < 2; ++i) {
        int cid = wid * 2 + i;
        gload16(Wb + cid * 512 + lane * 8, w_s + cid * 512);
    }
    {
        int r = tid >> 3, q = tid & 7;
        int n = n0 + r;
        float vals[16];
        if (n < n_rows) {
            #pragma unroll
            for (int j = 0; j < 4; ++j) {
                f32x4 v = ((const f32x4*)A)[(size_t)n * 32 + q * 4 + j];
                #pragma unroll
                for (int x = 0; x < 4; ++x) vals[j * 4 + x] = v[x];
            }
        } else {
            #pragma unroll
            for (int x = 0; x < 16; ++x) vals[x] = 0.f;
        }
        int sw = (r & 7) << 3;
        #pragma unroll
        for (int hh = 0; hh < 2; ++hh) {
            us8 pk;
            #pragma unroll
            for (int x = 0; x < 8; ++x) pk[x] = f2bf(vals[hh * 8 + x]);
            *(us8*)&a_s[r * 128 + ((q * 16 + hh * 8) ^ sw)] = pk;
        }
    }
    __syncthreads();

    const int og = (wid >> 2) * 32;
    const int rg = (wid & 3) * 32;
    const int lm = lane & 15, lh = lane >> 4;

    f32x4 acc[2][2];
    #pragma unroll
    for (int mt = 0; mt < 2; ++mt)
        #pragma unroll
        for (int nt = 0; nt < 2; ++nt) acc[mt][nt] = (f32x4){0.f, 0.f, 0.f, 0.f};

    #pragma unroll
    for (int ks = 0; ks < 4; ++ks) {
        int k8 = ks * 32 + lh * 8;
        bf16x8 af[2], wf[2];
        #pragma unroll
        for (int mt = 0; mt < 2; ++mt) {
            int m = rg + mt * 16 + lm;
            af[mt] = __builtin_bit_cast(bf16x8,
                *(const us8*)&a_s[m * 128 + (k8 ^ ((m & 7) << 3))]);
        }
        #pragma unroll
        for (int nt = 0; nt < 2; ++nt) {
            int n = og + nt * 16 + lm;
            wf[nt] = __builtin_bit_cast(bf16x8,
                *(const us8*)&w_s[n * 128 + (k8 ^ ((n & 7) << 3))]);
        }
        #pragma unroll
        for (int mt = 0; mt < 2; ++mt)
            #pragma unroll
            for (int nt = 0; nt < 2; ++nt)
                acc[mt][nt] = __builtin_amdgcn_mfma_f32_16x16x32_bf16(
                    af[mt], wf[nt], acc[mt][nt], 0, 0, 0);
    }

    #pragma unroll
    for (int nt = 0; nt < 2; ++nt) {
        int outc = og + nt * 16 + lm;
        #pragma unroll
        for (int mt = 0; mt < 2; ++mt) {
            int rbase = rg + mt * 16 + lh * 4;
            #pragma unroll
            for (int j = 0; j < 4; ++j) {
                int n = n0 + rbase + j;
                if (n < n_rows) {
                    h1b[(size_t)n * 128 + outc] = f2bf(acc[mt][nt][j]);
                    aggz[(size_t)n * 128 + outc] = 0.f;
                }
            }
        }
    }
}

// ---------------- fused node GEMM2+3 (reads h1b bf16 + agg f32) -------------
__global__ __launch_bounds__(1024, 4) void gemm23_fused(
    const ushort_t* __restrict__ h1b, const float* __restrict__ agg,
    const ushort_t* __restrict__ l2b, const float* __restrict__ b2,
    const ushort_t* __restrict__ lfb, const float* __restrict__ lb,
    float* __restrict__ outF, int n_rows)
{
    __shared__ ushort_t a_s[128 * 128];
    __shared__ ushort_t w_s[128 * 128];
    const int tid = threadIdx.x;
    const int n0 = blockIdx.x * 128;
    const int lane = tid & 63, wid = tid >> 6;

    #pragma unroll
    for (int i = 0; i < 2; ++i) {
        int cid = wid * 2 + i;
        gload16(l2b + cid * 512 + lane * 8, w_s + cid * 512);
    }
    {
        int r = tid >> 3, q = tid & 7;
        int n = n0 + r;
        float vals[16];
        if (n < n_rows) {
            us8 hb0 = *(const us8*)&h1b[(size_t)n * 128 + q * 16];
            us8 hb1 = *(const us8*)&h1b[(size_t)n * 128 + q * 16 + 8];
            #pragma unroll
            for (int j = 0; j < 4; ++j) {
                f32x4 av = ((const f32x4*)agg)[(size_t)n * 32 + q * 4 + j];
                #pragma unroll
                for (int x = 0; x < 4; ++x) {
                    int c = j * 4 + x;
                    float hv = bf2f(c < 8 ? hb0[c] : hb1[c - 8]);
                    vals[c] = hv + av[x];
                }
            }
        } else {
            #pragma unroll
            for (int x = 0; x < 16; ++x) vals[x] = 0.f;
        }
        int sw = (r & 7) << 3;
        #pragma unroll
        for (int hh = 0; hh < 2; ++hh) {
            us8 pk;
            #pragma unroll
            for (int x = 0; x < 8; ++x) pk[x] = f2bf(vals[hh * 8 + x]);
            *(us8*)&a_s[r * 128 + ((q * 16 + hh * 8) ^ sw)] = pk;
        }
    }
    __syncthreads();

    const int og = (wid >> 2) * 32;
    const int rg = (wid & 3) * 32;
    const int lm = lane & 15, lh = lane >> 4;

    f32x4 acc[2][2];
    #pragma unroll
    for (int mt = 0; mt < 2; ++mt)
        #pragma unroll
        for (int nt = 0; nt < 2; ++nt) acc[mt][nt] = (f32x4){0.f, 0.f, 0.f, 0.f};
    #pragma unroll
    for (int ks = 0; ks < 4; ++ks) {
        int k8 = ks * 32 + lh * 8;
        bf16x8 af[2], wf[2];
        #pragma unroll
        for (int mt = 0; mt < 2; ++mt) {
            int m = rg + mt * 16 + lm;
            af[mt] = __builtin_bit_cast(bf16x8,
                *(const us8*)&a_s[m * 128 + (k8 ^ ((m & 7) << 3))]);
        }
        #pragma unroll
        for (int nt = 0; nt < 2; ++nt) {
            int n = og + nt * 16 + lm;
            wf[nt] = __builtin_bit_cast(bf16x8,
                *(const us8*)&w_s[n * 128 + (k8 ^ ((n & 7) << 3))]);
        }
        #pragma unroll
        for (int mt = 0; mt < 2; ++mt)
            #pragma unroll
            for (int nt = 0; nt < 2; ++nt)
                acc[mt][nt] = __builtin_amdgcn_mfma_f32_16x16x32_bf16(
                    af[mt], wf[nt], acc[mt][nt], 0, 0, 0);
    }
    __syncthreads();        // all a_s / w_s reads complete

    #pragma unroll
    for (int i = 0; i < 2; ++i) {
        int cid = wid * 2 + i;
        gload16(lfb + cid * 512 + lane * 8, w_s + cid * 512);
    }
    #pragma unroll
    for (int nt = 0; nt < 2; ++nt) {
        int outc = og + nt * 16 + lm;
        float bv = b2[outc];
        #pragma unroll
        for (int mt = 0; mt < 2; ++mt) {
            int rbase = rg + mt * 16 + lh * 4;
            #pragma unroll
            for (int j = 0; j < 4; ++j) {
                int r = rbase + j;
                a_s[r * 128 + (outc ^ ((r & 7) << 3))] =
                    f2bf(ssp_fast(acc[mt][nt][j] + bv));
            }
        }
    }
    __syncthreads();

    f32x4 acc2[2][2];
    #pragma unroll
    for (int mt = 0; mt < 2; ++mt)
        #pragma unroll
        for (int nt = 0; nt < 2; ++nt) acc2[mt][nt] = (f32x4){0.f, 0.f, 0.f, 0.f};
    #pragma unroll
    for (int ks = 0; ks < 4; ++ks) {
        int k8 = ks * 32 + lh * 8;
        bf16x8 af[2], wf[2];
        #pragma unroll
        for (int mt = 0; mt < 2; ++mt) {
            int m = rg + mt * 16 + lm;
            af[mt] = __builtin_bit_cast(bf16x8,
                *(const us8*)&a_s[m * 128 + (k8 ^ ((m & 7) << 3))]);
        }
        #pragma unroll
        for (int nt = 0; nt < 2; ++nt) {
            int n = og + nt * 16 + lm;
            wf[nt] = __builtin_bit_cast(bf16x8,
                *(const us8*)&w_s[n * 128 + (k8 ^ ((n & 7) << 3))]);
        }
        #pragma unroll
        for (int mt = 0; mt < 2; ++mt)
            #pragma unroll
            for (int nt = 0; nt < 2; ++nt)
                acc2[mt][nt] = __builtin_amdgcn_mfma_f32_16x16x32_bf16(
                    af[mt], wf[nt], acc2[mt][nt], 0, 0, 0);
    }

    #pragma unroll
    for (int nt = 0; nt < 2; ++nt) {
        int outc = og + nt * 16 + lm;
        float bv = lb[outc];
        #pragma unroll
        for (int mt = 0; mt < 2; ++mt) {
            int rbase = rg + mt * 16 + lh * 4;
            #pragma unroll
            for (int j = 0; j < 4; ++j) {
                int n = n0 + rbase + j;
                if (n < n_rows)
                    outF[(size_t)n * 128 + outc] = acc2[mt][nt][j] + bv;
            }
        }
    }
}

// ---------------- fused edge MLP + message + segmented aggregation ---------
// 256 thr = 4 waves (4 out-groups x 1 edge-group); 64 CSR positions/block.
// ~25 KB LDS -> 6 blocks/CU (24 waves) for latency hiding.
__global__ __launch_bounds__(256, 6) void edge_fused(
    const float* __restrict__ ea, const int4* __restrict__ sidecar,
    const ushort_t* __restrict__ w0g, const ushort_t* __restrict__ w2g,
    const float* __restrict__ b0g, const float* __restrict__ b2g,
    const ushort_t* __restrict__ h1b, float* __restrict__ agg, int E)
{
    __shared__ __align__(16) char blob[25344];
    ushort_t* ea_s = (ushort_t*)blob;             // 8 KB  [0,8192)
    ushort_t* u_s  = (ushort_t*)(blob + 8192);    // 16 KB [8192,24576)
    ushort_t* m_sb = (ushort_t*)blob;             // 16 KB overlay (phase D/E)
    float* cws = (float*)(blob + 24576);          // 256 B
    int* srcs  = (int*)(blob + 24832);            // 256 B
    int* dsts  = (int*)(blob + 25088);            // 256 B

    const int tid = threadIdx.x;
    const int p0 = blockIdx.x * 64;
    const int lane = tid & 63, wid = tid >> 6;
    const int out0w = wid * 32;          // 4 out-groups of 32
    const int lm = lane & 15, lh = lane >> 4;

    // ---- stage ea rows by gather: 4 threads/row, 8 float2 each ----
    {
        int r = tid >> 2, q = tid & 3;   // 64 rows x 4 chunks of 16 cols
        int p = p0 + r;
        int eidx = ((const int*)sidecar)[(size_t)p * 4 + 3];
        const float2* row2 = (const float2*)(ea + (size_t)eidx * 50);
        us8 pk0 = {0, 0, 0, 0, 0, 0, 0, 0};
        us8 pk1 = {0, 0, 0, 0, 0, 0, 0, 0};
        if (q < 3) {
            #pragma unroll
            for (int j = 0; j < 4; ++j) {
                float2 f = row2[q * 8 + j];
                pk0[2 * j]     = f2bf(f.x);
                pk0[2 * j + 1] = f2bf(f.y);
            }
            #pragma unroll
            for (int j = 0; j < 4; ++j) {
                float2 f = row2[q * 8 + 4 + j];
                pk1[2 * j]     = f2bf(f.x);
                pk1[2 * j + 1] = f2bf(f.y);
            }
        } else {
            float2 f = row2[24];          // cols 48,49
            pk0[0] = f2bf(f.x);
            pk0[1] = f2bf(f.y);
        }
        int sw = (r & 7) << 3;
        *(us8*)&ea_s[r * 64 + ((q * 16)     ^ sw)] = pk0;
        *(us8*)&ea_s[r * 64 + ((q * 16 + 8) ^ sw)] = pk1;
    }
    if (tid < 64) {
        int4 sc = sidecar[p0 + tid];
        srcs[tid] = sc.x; dsts[tid] = sc.y; cws[tid] = __int_as_float(sc.z);
    }

    // w0 fragments (L2-resident)
    bf16x8 w0f[2][2];
    #pragma unroll
    for (int ks = 0; ks < 2; ++ks)
        #pragma unroll
        for (int mt = 0; mt < 2; ++mt) {
            int n = out0w + mt * 16 + lm;
            w0f[ks][mt] = __builtin_bit_cast(bf16x8,
                *(const us8*)&w0g[n * 64 + ks * 32 + lh * 8]);
        }
    __syncthreads();

    // ---- GEMM1: t^T = w0 * ea^T  (K = 64 padded) ----
    f32x4 acc1[2][4];
    #pragma unroll
    for (int mt = 0; mt < 2; ++mt)
        #pragma unroll
        for (int nt = 0; nt < 4; ++nt) acc1[mt][nt] = (f32x4){0.f, 0.f, 0.f, 0.f};
    #pragma unroll
    for (int ks = 0; ks < 2; ++ks) {
        int k8 = ks * 32 + lh * 8;
        #pragma unroll
        for (int nt = 0; nt < 4; ++nt) {
            int e = nt * 16 + lm;
            bf16x8 be = __builtin_bit_cast(bf16x8,
                *(const us8*)&ea_s[e * 64 + (k8 ^ ((e & 7) << 3))]);
            #pragma unroll
            for (int mt = 0; mt < 2; ++mt)
                acc1[mt][nt] = __builtin_amdgcn_mfma_f32_16x16x32_bf16(
                    w0f[ks][mt], be, acc1[mt][nt], 0, 0, 0);
        }
    }

    // epilogue1: u = ssp(t + b0) -> packed 4xbf16 ds_write_b64
    #pragma unroll
    for (int mt = 0; mt < 2; ++mt) {
        int out0 = out0w + mt * 16 + lh * 4;
        f32x4 b0v = *(const f32x4*)&b0g[out0];
        #pragma unroll
        for (int nt = 0; nt < 4; ++nt) {
            int e = nt * 16 + lm;
            us4 pk;
            #pragma unroll
            for (int j = 0; j < 4; ++j)
                pk[j] = f2bf(ssp_fast(acc1[mt][nt][j] + b0v[j]));
            *(us4*)&u_s[e * 128 + (out0 ^ ((e & 7) << 3))] = pk;
        }
    }

    // w2 fragments loaded here (L2-hit, hidden under epilogue/barrier)
    bf16x8 w2f[4][2];
    #pragma unroll
    for (int ks = 0; ks < 4; ++ks)
        #pragma unroll
        for (int mt = 0; mt < 2; ++mt) {
            int n = out0w + mt * 16 + lm;
            w2f[ks][mt] = __builtin_bit_cast(bf16x8,
                *(const us8*)&w2g[n * 128 + ks * 32 + lh * 8]);
        }
    __syncthreads();

    // ---- GEMM2: W^T = w2 * u^T  (K = 128) ----
    f32x4 acc2[2][4];
    #pragma unroll
    for (int mt = 0; mt < 2; ++mt)
        #pragma unroll
        for (int nt = 0; nt < 4; ++nt) acc2[mt][nt] = (f32x4){0.f, 0.f, 0.f, 0.f};
    #pragma unroll
    for (int ks = 0; ks < 4; ++ks) {
        int k8 = ks * 32 + lh * 8;
        #pragma unroll
        for (int nt = 0; nt < 4; ++nt) {
            int e = nt * 16 + lm;
            bf16x8 be = __builtin_bit_cast(bf16x8,
                *(const us8*)&u_s[e * 128 + (k8 ^ ((e & 7) << 3))]);
            #pragma unroll
            for (int mt = 0; mt < 2; ++mt)
                acc2[mt][nt] = __builtin_amdgcn_mfma_f32_16x16x32_bf16(
                    w2f[ks][mt], be, acc2[mt][nt], 0, 0, 0);
        }
    }
    __syncthreads();    // ea_s/u_s reads done; m_sb overlay now safe

    // ---- phase D: W' = c*(W+b2) -> bf16 LDS (swizzled), no h1 ----
    #pragma unroll
    for (int mt = 0; mt < 2; ++mt) {
        int out0 = out0w + mt * 16 + lh * 4;
        f32x4 b2v = *(const f32x4*)&b2g[out0];
        #pragma unroll
        for (int nt = 0; nt < 4; ++nt) {
            int e = nt * 16 + lm;
            float cvv = cws[e];
            us4 pk;
            #pragma unroll
            for (int j = 0; j < 4; ++j)
                pk[j] = f2bf(cvv * (acc2[mt][nt][j] + b2v[j]));
            *(us4*)&m_sb[e * 128 + (out0 ^ ((e & 7) << 2))] = pk;
        }
    }

    // hoisted phase-E h1 prefetch (accumulators dead -> regs free)
    const int i0 = wid * 16;             // 4 segments x 16 edges
    us2 h1r[16];
    #pragma unroll
    for (int j = 0; j < 16; ++j) {
        int s = srcs[i0 + j];
        h1r[j] = *(const us2*)&h1b[(size_t)s * 128 + lane * 2];
    }
    __syncthreads();

    // ---- phase E: segmented reduce + atomics ----
    {
        const int cp = lane;             // ch pair: channels 2cp, 2cp+1
        float sx = 0.f, sy = 0.f;
        int prev = dsts[i0];
        #pragma unroll
        for (int j = 0; j < 16; ++j) {
            int i = i0 + j;
            int d = dsts[i];
            us2 wv = *(const us2*)&m_sb[i * 128 + ((cp * 2) ^ ((i & 7) << 2))];
            if (d != prev) {
                atomicAdd(&agg[(size_t)prev * 128 + cp * 2], sx);
                atomicAdd(&agg[(size_t)prev * 128 + cp * 2 + 1], sy);
                sx = 0.f; sy = 0.f; prev = d;
            }
            sx += bf2f(wv[0]) * bf2f(h1r[j][0]);
            sy += bf2f(wv[1]) * bf2f(h1r[j][1]);
        }
        atomicAdd(&agg[(size_t)prev * 128 + cp * 2], sx);
        atomicAdd(&agg[(size_t)prev * 128 + cp * 2 + 1], sy);
    }
}

extern "C" void kernel_launch(void* const* d_in, const int* in_sizes, int n_in,
                              void* d_out, int out_size, void* d_ws, size_t ws_size,
                              hipStream_t stream) {
    const float* h       = (const float*)d_in[0];
    const int*   ei      = (const int*)  d_in[1];
    const float* ew      = (const float*)d_in[2];
    const float* ea      = (const float*)d_in[3];
    const float* mlp_w0  = (const float*)d_in[4];
    const float* mlp_b0  = (const float*)d_in[5];
    const float* mlp_w2  = (const float*)d_in[6];
    const float* mlp_b2  = (const float*)d_in[7];
    const float* lin1_w  = (const float*)d_in[8];
    const float* lin2_w  = (const float*)d_in[9];
    const float* lin2_b  = (const float*)d_in[10];
    const float* lin_w   = (const float*)d_in[11];
    const float* lin_b   = (const float*)d_in[12];
    float* out = (float*)d_out;
    float* ws  = (float*)d_ws;

    const int N = in_sizes[0] / HID;            // 50000
    const int E = in_sizes[2];                  // 600000
    const int PADE = (E + 63) & ~63;            // 600000 (exact)
    const int NODE_PAD = (N + 256) & ~255;      // 50176
    const int NSB = (N + 1023) / 1024;          // 49 scan blocks

    // ---- workspace layout (f32 slots) ----
    float* agg   = ws;                                   // N*128
    ushort_t* h1b = (ushort_t*)(agg + (size_t)N * 128);  // N*128 us
    ushort_t* l1b = (ushort_t*)((float*)h1b + (size_t)N * 64);
    ushort_t* l2b = l1b + 16384;
    ushort_t* lfb = l2b + 16384;
    ushort_t* w0g = lfb + 16384;                         // 8192 us
    ushort_t* w2g = w0g + 8192;                          // 16384 us
    int* counts  = (int*)(w2g + 16384);                  // NODE_PAD
    int* off     = counts + NODE_PAD;                    // NODE_PAD
    int* bsum    = off + NODE_PAD;                       // 64
    int* slot    = bsum + 64;                            // E
    int4* sidecar = (int4*)(slot + E);                   // PADE int4

    const int* srcI = ei;
    const int* dstI = ei + E;

    hipMemsetAsync(counts, 0, (size_t)NODE_PAD * 4, stream);

    const int nsp = (PADE - E) * 4;    // sidecar pad ints
    int total_threads = E + 73728 + nsp;
    prep_count<<<(total_threads + 255) / 256, 256, 0, stream>>>(
        dstI, counts, slot, lin1_w, lin2_w, lin_w, mlp_w0, mlp_w2,
        l1b, l2b, lfb, w0g, w2g, (int*)(sidecar + E), E, nsp);

    scan1<<<NSB, 1024, 0, stream>>>(counts, off, bsum, N);

    int ngrid = (N + 127) / 128;                // 391
    int pb    = (E + 1023) / 1024;              // 586
    // fused: h1b = bf16(h @ lin1^T) + agg=0  ||  sidecar permute (+scan2)
    h1_and_permute<<<ngrid + pb, 1024, 0, stream>>>(
        h, l1b, h1b, agg, N, ngrid,
        srcI, dstI, slot, off, bsum, NSB, ew, sidecar, E);

    // fused edge MLP + message + aggregation (ea gathered in-kernel)
    edge_fused<<<PADE / 64, 256, 0, stream>>>(ea, sidecar, w0g, w2g,
                                              mlp_b0, mlp_b2, h1b, agg, E);

    // out = ssp((h1+agg)@lin2^T + b2) @ lin^T + lin_b
    gemm23_fused<<<ngrid, 1024, 0, stream>>>(h1b, agg, l2b, lin2_b,
                                             lfb, lin_b, out, N);
}